// Round 1
// baseline (312.988 us; speedup 1.0000x reference)
//
#include <hip/hip_runtime.h>
#include <math.h>

#ifndef __has_builtin
#define __has_builtin(x) 0
#endif

#define NPTS   131072
#define FCH    16
#define CSND   343.0f
#define PB     16          // points per workgroup pass
#define BLOCK  512         // 8 waves
#define GRID   512         // 2 WGs/CU * 256 CUs
#define NBLK   (NPTS / PB) // 8192

typedef _Float16 h2 __attribute__((ext_vector_type(2)));

static __device__ __forceinline__ unsigned pack2(float a, float b) {
  h2 v; v[0] = (_Float16)a; v[1] = (_Float16)b;
  return __builtin_bit_cast(unsigned, v);
}

static __device__ __forceinline__ float fdot2u(unsigned a, unsigned b, float c) {
#if __has_builtin(__builtin_amdgcn_fdot2)
  return __builtin_amdgcn_fdot2(__builtin_bit_cast(h2, a), __builtin_bit_cast(h2, b), c, false);
#else
  h2 ha = __builtin_bit_cast(h2, a), hb = __builtin_bit_cast(h2, b);
  return c + (float)ha[0] * (float)hb[0] + (float)ha[1] * (float)hb[1];
#endif
}

static __device__ __forceinline__ float mytanh(float x) {
  float ax = fabsf(x);
  float e  = __expf(-2.0f * ax);
  float r  = (1.0f - e) * __builtin_amdgcn_rcpf(1.0f + e);
  return copysignf(r, x);
}

__global__ __launch_bounds__(BLOCK, 4) void helmholtz_kernel(
    const float* __restrict__ x,      // [N,3]
    const float* __restrict__ omega,  // [16]
    const float* __restrict__ W1,     // [3,128]
    const float* __restrict__ b1,     // [128]
    const float* __restrict__ W2,     // [128,128]
    const float* __restrict__ b2,     // [128]
    const float* __restrict__ W3,     // [128,32]
    const float* __restrict__ b3,     // [32]
    float* __restrict__ out)
{
  // LDS: 32768 + 20480 + 8192 + 1536 + 512 + 512 + 128 = 64128 B
  __shared__ unsigned s_w2[64 * 128];   // half2 pairs over K: {W2[2i2][j], W2[2i2+1][j]}
  __shared__ unsigned s_act[PB * 5 * 64]; // activations as half2 pairs; reused as h/g after step2
  __shared__ unsigned s_w3[64 * 32];    // half2 pairs over J: {W3[2j2][c], W3[2j2+1][c]}
  __shared__ float s_w1[3 * 128];
  __shared__ float s_b1[128];
  __shared__ float s_b2[128];
  __shared__ float s_b3[32];

  const int tid = threadIdx.x;
  const int wv  = tid >> 6;   // wave 0..7
  const int l   = tid & 63;   // lane

  // ---- stage weights once per WG ----
  for (int idx = tid; idx < 64 * 128; idx += BLOCK) {
    int i2 = idx >> 7, j = idx & 127;
    s_w2[idx] = pack2(W2[(2 * i2) * 128 + j], W2[(2 * i2 + 1) * 128 + j]);
  }
  for (int idx = tid; idx < 64 * 32; idx += BLOCK) {
    int j2 = idx >> 5, c = idx & 31;
    s_w3[idx] = pack2(W3[(2 * j2) * 32 + c], W3[(2 * j2 + 1) * 32 + c]);
  }
  if (tid < 384) s_w1[tid] = W1[tid];
  if (tid < 128) s_b1[tid] = b1[tid];
  if (tid >= 128 && tid < 256) s_b2[tid - 128] = b2[tid - 128];
  if (tid >= 256 && tid < 288) s_b3[tid - 256] = b3[tid - 256];

  const int c_ch = l & 31;
  float k2reg = 0.0f;
  if (c_ch >= 1 && c_ch < FCH) {
    float om = omega[c_ch] * (1.0f / CSND);
    k2reg = om * om;
  }
  float wsum = 0.0f;

  const int r0 = (2 * wv)     * 5 * 64;  // act dword base, point 2w
  const int r1 = (2 * wv + 1) * 5 * 64;  // act dword base, point 2w+1

  for (int blk = blockIdx.x; blk < NBLK; blk += gridDim.x) {
    const int pbase = blk * PB;
    __syncthreads();  // protects s_act reuse vs previous pass's step 3 / staging

    // ---- step 1: layer 1 + the 5 layer-2 input vectors (f16 pairs in LDS) ----
    for (int idx = tid; idx < PB * 64; idx += BLOCK) {
      int p = idx >> 6, i2 = idx & 63;
      const float* xp = x + (size_t)(pbase + p) * 3;
      float x0 = xp[0], x1 = xp[1], x2 = xp[2];
      float tv[2], a1v[2], a2v[2], a3v[2], a4v[2];
#pragma unroll
      for (int b = 0; b < 2; b++) {
        int i = 2 * i2 + b;
        float w0 = s_w1[i], w1v = s_w1[128 + i], w2v = s_w1[256 + i];
        float z = x0 * w0 + x1 * w1v + x2 * w2v + s_b1[i];
        float t = mytanh(z);
        float s = 1.0f - t * t;
        tv[b]  = t;
        a1v[b] = s * w0; a2v[b] = s * w1v; a3v[b] = s * w2v;
        a4v[b] = -2.0f * t * s * (w0 * w0 + w1v * w1v + w2v * w2v); // c1 (pre-summed over d)
      }
      int base = p * 5 * 64 + i2;
      s_act[base      ] = pack2(tv[0],  tv[1]);   // h1
      s_act[base +  64] = pack2(a1v[0], a1v[1]);  // dh1 dir0
      s_act[base + 128] = pack2(a2v[0], a2v[1]);  // dh1 dir1
      s_act[base + 192] = pack2(a3v[0], a3v[1]);  // dh1 dir2
      s_act[base + 256] = pack2(a4v[0], a4v[1]);  // c1
    }
    __syncthreads();

    // ---- step 2: 5 matvecs vs W2 via v_dot2_f32_f16; lane owns j=l and j=l+64 ----
    float acc[2][5][2];
#pragma unroll
    for (int pp = 0; pp < 2; pp++)
#pragma unroll
      for (int v = 0; v < 5; v++) { acc[pp][v][0] = 0.0f; acc[pp][v][1] = 0.0f; }

    for (int i2b = 0; i2b < 64; i2b += 4) {
      unsigned a0[5][4], a1b[5][4];
#pragma unroll
      for (int v = 0; v < 5; v++) {
        uint4 q0 = *(const uint4*)&s_act[r0 + v * 64 + i2b];
        uint4 q1 = *(const uint4*)&s_act[r1 + v * 64 + i2b];
        a0[v][0] = q0.x; a0[v][1] = q0.y; a0[v][2] = q0.z; a0[v][3] = q0.w;
        a1b[v][0] = q1.x; a1b[v][1] = q1.y; a1b[v][2] = q1.z; a1b[v][3] = q1.w;
      }
#pragma unroll
      for (int k = 0; k < 4; k++) {
        unsigned wa = s_w2[(i2b + k) * 128 + l];
        unsigned wb = s_w2[(i2b + k) * 128 + l + 64];
#pragma unroll
        for (int v = 0; v < 5; v++) {
          acc[0][v][0] = fdot2u(a0[v][k],  wa, acc[0][v][0]);
          acc[0][v][1] = fdot2u(a0[v][k],  wb, acc[0][v][1]);
          acc[1][v][0] = fdot2u(a1b[v][k], wa, acc[1][v][0]);
          acc[1][v][1] = fdot2u(a1b[v][k], wb, acc[1][v][1]);
        }
      }
    }
    __syncthreads();  // all waves done reading s_act before we overwrite it with h/g

    // ---- layer-2 elementwise (in registers), write h2 and G as f16 pairs ----
    {
      _Float16* hgh = (_Float16*)s_act; // layout dword: [p][j2][2] = {h2 pair, g pair}
#pragma unroll
      for (int pp = 0; pp < 2; pp++) {
        int p = 2 * wv + pp;
#pragma unroll
        for (int jj = 0; jj < 2; jj++) {
          int j = l + 64 * jj;
          float z2 = acc[pp][0][jj] + s_b2[j];
          float d0 = acc[pp][1][jj], d1 = acc[pp][2][jj], d2 = acc[pp][3][jj];
          float Av = acc[pp][4][jj];
          float t2 = mytanh(z2);
          float s2 = 1.0f - t2 * t2;
          float Bv = d0 * d0 + d1 * d1 + d2 * d2;
          float g  = s2 * (Av - 2.0f * t2 * Bv);   // Σ_d ∂²h2/∂x_d²
          int hb = p * 256 + (j >> 1) * 4 + (j & 1);
          hgh[hb]     = (_Float16)t2;
          hgh[hb + 2] = (_Float16)g;
        }
      }
    }
    __syncthreads();

    // ---- step 3: y = h2@W3 + b3, lap = G@W3; lane owns (p = 2w + l/32, c = l%32) ----
    {
      int p = 2 * wv + (l >> 5);
      float accy = s_b3[c_ch];
      float accl = 0.0f;
      const uint2* hgp = (const uint2*)s_act;
#pragma unroll 4
      for (int j2 = 0; j2 < 64; j2++) {
        uint2 hg = hgp[p * 64 + j2];
        unsigned wv3 = s_w3[j2 * 32 + c_ch];
        accy = fdot2u(hg.x, wv3, accy);
        accl = fdot2u(hg.y, wv3, accl);
      }
      // pair real channel c with imag channel c+16 (lane l+16, same point)
      float yim = __shfl_down(accy, 16, 64);
      float lim = __shfl_down(accl, 16, 64);
      if (c_ch >= 1 && c_ch < FCH) {
        float re = accl + k2reg * accy;
        float im = lim  + k2reg * yim;
        wsum += re * re + im * im;
      }
    }
  }

  // ---- final: wave reduce, one atomic per wave ----
#pragma unroll
  for (int off = 32; off > 0; off >>= 1)
    wsum += __shfl_down(wsum, off, 64);
  if (l == 0)
    atomicAdd(out, wsum * (1.0f / ((float)NPTS * (float)(FCH - 1))));
}

extern "C" void kernel_launch(void* const* d_in, const int* in_sizes, int n_in,
                              void* d_out, int out_size, void* d_ws, size_t ws_size,
                              hipStream_t stream) {
  const float* x     = (const float*)d_in[0];
  const float* omega = (const float*)d_in[1];
  const float* W1    = (const float*)d_in[2];
  const float* b1    = (const float*)d_in[3];
  const float* W2    = (const float*)d_in[4];
  const float* b2    = (const float*)d_in[5];
  const float* W3    = (const float*)d_in[6];
  const float* b3    = (const float*)d_in[7];
  float* out = (float*)d_out;

  hipMemsetAsync(out, 0, sizeof(float), stream);
  helmholtz_kernel<<<GRID, BLOCK, 0, stream>>>(x, omega, W1, b1, W2, b2, W3, b3, out);
}

// Round 3
// 130.581 us; speedup vs baseline: 2.3969x; 2.3969x over previous
//
#include <hip/hip_runtime.h>
#include <math.h>

#ifndef __has_builtin
#define __has_builtin(x) 0
#endif

#define NPTS   131072
#define FCH    16
#define CSND   343.0f
#define PB     16           // points per workgroup pass
#define BLOCK  256          // 4 waves
#define GRID   512          // 2 WG/CU * 256 CUs
#define NBLK   (NPTS / PB)  // 8192

typedef _Float16 half8 __attribute__((ext_vector_type(8)));
typedef _Float16 half2v __attribute__((ext_vector_type(2)));
typedef float    f32x4 __attribute__((ext_vector_type(4)));

static __device__ __forceinline__ unsigned pack2(float a, float b) {
#if __has_builtin(__builtin_amdgcn_cvt_pkrtz)
  return __builtin_bit_cast(unsigned, __builtin_amdgcn_cvt_pkrtz(a, b));
#else
  half2v v; v[0] = (_Float16)a; v[1] = (_Float16)b;
  return __builtin_bit_cast(unsigned, v);
#endif
}

static __device__ __forceinline__ float mytanh(float x) {
  float ax = fabsf(x);
  float e  = __expf(-2.0f * ax);
  float r  = (1.0f - e) * __builtin_amdgcn_rcpf(1.0f + e);
  return copysignf(r, x);
}

// LDS layout (dwords):
//   s_w2t[128][64] : W2^T f16, row n (output j), 16 chunks of 8 k-values,
//                    chunk c stored at position (c ^ (n&15))  -> conflict-free b128
//   s_w3t[32][64]  : W3^T f16, same scheme
//   s_A[5120]      : 80 rows x 64 dwords, rows = v*16+p (v=0..4: h1,d0,d1,d2,c1),
//                    chunk swizzle (c ^ (row&15)). Reused after step2 as:
//                      u16 rows 0..15  = h2[p][j], rows 16..31 = G[p][j]  (dwords 0..2047)
//                      dwords 2048..   = y[16][33] f32, lap[16][33] f32 at +528

__global__ __launch_bounds__(BLOCK, 2) void helmholtz_kernel(
    const float* __restrict__ x,      // [N,3]
    const float* __restrict__ omega,  // [16]
    const float* __restrict__ W1,     // [3,128]
    const float* __restrict__ b1,     // [128]
    const float* __restrict__ W2,     // [128,128]
    const float* __restrict__ b2,     // [128]
    const float* __restrict__ W3,     // [128,32]
    const float* __restrict__ b3,     // [32]
    float* __restrict__ out)
{
  __shared__ unsigned s_w2t[128 * 64];  // 32 KB
  __shared__ unsigned s_w3t[32 * 64];   //  8 KB
  __shared__ unsigned s_A[80 * 64];     // 20 KB   (total 60 KB -> 2 WG/CU)

  const int tid  = threadIdx.x;
  const int w    = tid >> 6;   // wave 0..3
  const int l    = tid & 63;
  const int col  = l & 15;
  const int quad = l >> 4;

  // ---- one-time staging: W2^T, W3^T as swizzled f16 ----
  for (int task = tid; task < 2048; task += BLOCK) {
    int n = task & 127, c = task >> 7;
    unsigned pk[4];
#pragma unroll
    for (int d = 0; d < 4; d++)
      pk[d] = pack2(W2[(8 * c + 2 * d) * 128 + n], W2[(8 * c + 2 * d + 1) * 128 + n]);
    uint4 q = make_uint4(pk[0], pk[1], pk[2], pk[3]);
    *(uint4*)&s_w2t[n * 64 + ((c ^ (n & 15)) << 2)] = q;
  }
  for (int task = tid; task < 512; task += BLOCK) {
    int n = task & 31, c = task >> 5;
    unsigned pk[4];
#pragma unroll
    for (int d = 0; d < 4; d++)
      pk[d] = pack2(W3[(8 * c + 2 * d) * 32 + n], W3[(8 * c + 2 * d + 1) * 32 + n]);
    uint4 q = make_uint4(pk[0], pk[1], pk[2], pk[3]);
    *(uint4*)&s_w3t[n * 64 + ((c ^ (n & 15)) << 2)] = q;
  }

  // ---- persistent per-thread registers ----
  // phase A: this thread always handles input-unit pair i0=2*i2, i1=2*i2+1
  const int i2 = tid & 63;
  const float a0x = W1[2 * i2],       a0y = W1[128 + 2 * i2],  a0z = W1[256 + 2 * i2];
  const float a1x = W1[2 * i2 + 1],   a1y = W1[129 + 2 * i2],  a1z = W1[257 + 2 * i2];
  const float bb0 = b1[2 * i2],       bb1 = b1[2 * i2 + 1];
  const float wsq0 = a0x * a0x + a0y * a0y + a0z * a0z;
  const float wsq1 = a1x * a1x + a1y * a1y + a1z * a1z;
  // phase C: wave w owns output cols j = w*32 + col and + 16
  const float b2r0 = b2[w * 32 + col];
  const float b2r1 = b2[w * 32 + 16 + col];
  // phase E: thread owns (point p = tid>>4, channel cE = (tid&15)+1)
  const bool  activeE = (tid & 15) < 15;
  const int   cE = (tid & 15) + 1;
  float k2E = 0.0f, b3a = 0.0f, b3b = 0.0f;
  if (activeE) {
    float om = omega[cE] * (1.0f / CSND);
    k2E = om * om;
    b3a = b3[cE];
    b3b = b3[cE + 16];
  }

  float wsum = 0.0f;

  for (int blk = blockIdx.x; blk < NBLK; blk += gridDim.x) {
    const int pbase = blk * PB;
    __syncthreads();  // (1) previous pass's phase E done; s_A free

    // ---- phase A: layer 1 + 5 layer-2 input vectors -> s_A (f16, swizzled) ----
#pragma unroll
    for (int it = 0; it < 4; it++) {
      int p = (tid >> 6) * 4 + it;
      const float* xp = x + (size_t)(pbase + p) * 3;
      float x0 = xp[0], x1 = xp[1], x2 = xp[2];
      float z0 = fmaf(x0, a0x, fmaf(x1, a0y, fmaf(x2, a0z, bb0)));
      float z1 = fmaf(x0, a1x, fmaf(x1, a1y, fmaf(x2, a1z, bb1)));
      float t0 = mytanh(z0), t1 = mytanh(z1);
      float s0 = 1.0f - t0 * t0, s1 = 1.0f - t1 * t1;
      unsigned u_h  = pack2(t0, t1);
      unsigned u_d0 = pack2(s0 * a0x, s1 * a1x);
      unsigned u_d1 = pack2(s0 * a0y, s1 * a1y);
      unsigned u_d2 = pack2(s0 * a0z, s1 * a1z);
      unsigned u_c  = pack2(-2.0f * t0 * s0 * wsq0, -2.0f * t1 * s1 * wsq1);
      int dcol = (((i2 >> 2) ^ p) << 2) + (i2 & 3);
      s_A[(p)      * 64 + dcol] = u_h;
      s_A[(16 + p) * 64 + dcol] = u_d0;
      s_A[(32 + p) * 64 + dcol] = u_d1;
      s_A[(48 + p) * 64 + dcol] = u_d2;
      s_A[(64 + p) * 64 + dcol] = u_c;
    }
    __syncthreads();  // (2)

    // ---- phase B: step-2 GEMM  [80 x 128] x [128 x 128] via MFMA ----
    f32x4 acc[5][2];
#pragma unroll
    for (int mt = 0; mt < 5; mt++)
#pragma unroll
      for (int ntl = 0; ntl < 2; ntl++)
        acc[mt][ntl] = (f32x4){0.0f, 0.0f, 0.0f, 0.0f};

    half8 bfrag[2][4];
#pragma unroll
    for (int ntl = 0; ntl < 2; ntl++) {
      int n = (2 * w + ntl) * 16 + col;
#pragma unroll
      for (int ks = 0; ks < 4; ks++) {
        int c = (ks * 4 + quad) ^ (n & 15);
        bfrag[ntl][ks] = *(const half8*)&s_w2t[n * 64 + (c << 2)];
      }
    }
#pragma unroll
    for (int mt = 0; mt < 5; mt++) {
      int m = mt * 16 + col;
#pragma unroll
      for (int ks = 0; ks < 4; ks++) {
        int c = (ks * 4 + quad) ^ (m & 15);
        half8 af = *(const half8*)&s_A[m * 64 + (c << 2)];
        acc[mt][0] = __builtin_amdgcn_mfma_f32_16x16x32_f16(af, bfrag[0][ks], acc[mt][0], 0, 0, 0);
        acc[mt][1] = __builtin_amdgcn_mfma_f32_16x16x32_f16(af, bfrag[1][ks], acc[mt][1], 0, 0, 0);
      }
    }
    __syncthreads();  // (3) all waves done reading s_A

    // ---- phase C: layer-2 elementwise in registers; write h2/G f16 into s_A ----
    {
      _Float16* hg = (_Float16*)s_A;
#pragma unroll
      for (int ntl = 0; ntl < 2; ntl++) {
        int j = (2 * w + ntl) * 16 + col;
        int chunkj = j >> 3;
        float b2v = ntl ? b2r1 : b2r0;
#pragma unroll
        for (int r = 0; r < 4; r++) {
          int p = quad * 4 + r;
          float z2 = acc[0][ntl][r] + b2v;
          float d0 = acc[1][ntl][r], d1 = acc[2][ntl][r], d2 = acc[3][ntl][r];
          float Av = acc[4][ntl][r];
          float t2 = mytanh(z2);
          float s2 = 1.0f - t2 * t2;
          float g  = s2 * (Av - 2.0f * t2 * (d0 * d0 + d1 * d1 + d2 * d2));
          int base = ((chunkj ^ p) << 3) + (j & 7);
          hg[p * 128 + base]        = (_Float16)t2;   // h2 rows 0..15
          hg[(16 + p) * 128 + base] = (_Float16)g;    // G  rows 16..31
        }
      }
    }
    __syncthreads();  // (4)

    // ---- phase D: step-3 GEMM  [32 x 128] x [128 x 32]; wave w owns one 16x16 tile ----
    {
      int mtp = w >> 1, ntp = w & 1;
      int mrow = mtp * 16 + col;
      int n    = ntp * 16 + col;
      f32x4 dacc = (f32x4){0.0f, 0.0f, 0.0f, 0.0f};
#pragma unroll
      for (int ks = 0; ks < 4; ks++) {
        int ca = (ks * 4 + quad) ^ (mrow & 15);
        half8 af = *(const half8*)&s_A[mrow * 64 + (ca << 2)];
        int cb = (ks * 4 + quad) ^ (n & 15);
        half8 bf = *(const half8*)&s_w3t[n * 64 + (cb << 2)];
        dacc = __builtin_amdgcn_mfma_f32_16x16x32_f16(af, bf, dacc, 0, 0, 0);
      }
      float* ylds = (float*)&s_A[2048];   // y[16][33] then lap[16][33]
      int base = mtp ? 528 : 0;
#pragma unroll
      for (int r = 0; r < 4; r++) {
        int p = quad * 4 + r;
        ylds[base + p * 33 + ntp * 16 + col] = dacc[r];
      }
    }
    __syncthreads();  // (5)

    // ---- phase E: residual ----
    if (activeE) {
      const float* ylds = (const float*)&s_A[2048];
      int p = tid >> 4;
      float yre = ylds[p * 33 + cE] + b3a;
      float yim = ylds[p * 33 + cE + 16] + b3b;
      float lre = ylds[528 + p * 33 + cE];
      float lim = ylds[528 + p * 33 + cE + 16];
      float re = fmaf(k2E, yre, lre);
      float im = fmaf(k2E, yim, lim);
      wsum += re * re + im * im;
    }
  }

  // ---- final: wave reduce, one atomic per wave ----
#pragma unroll
  for (int off = 32; off > 0; off >>= 1)
    wsum += __shfl_down(wsum, off, 64);
  if (l == 0)
    atomicAdd(out, wsum * (1.0f / ((float)NPTS * (float)(FCH - 1))));
}

extern "C" void kernel_launch(void* const* d_in, const int* in_sizes, int n_in,
                              void* d_out, int out_size, void* d_ws, size_t ws_size,
                              hipStream_t stream) {
  const float* x     = (const float*)d_in[0];
  const float* omega = (const float*)d_in[1];
  const float* W1    = (const float*)d_in[2];
  const float* b1    = (const float*)d_in[3];
  const float* W2    = (const float*)d_in[4];
  const float* b2    = (const float*)d_in[5];
  const float* W3    = (const float*)d_in[6];
  const float* b3    = (const float*)d_in[7];
  float* out = (float*)d_out;

  (void)hipMemsetAsync(out, 0, sizeof(float), stream);
  helmholtz_kernel<<<GRID, BLOCK, 0, stream>>>(x, omega, W1, b1, W2, b2, W3, b3, out);
}